// Round 10
// baseline (234.232 us; speedup 1.0000x reference)
//
#include <hip/hip_runtime.h>

// NCC loss, win=9, (1,1,160,192,224) fp32 -> scalar. Fully fused, round 17
// (2nd resubmit: R9 bench failed on container acquisition, not the kernel).
// R16 post-mortem: all three changes regressed (conflicts 2.4M, 3MB spill,
// +9MB fetch) -> reverted. Base = R12 (58.6us warm, best).
// Latency audit of R12: ~430 stall-cycles per block-phase. w_load(z+3) is
// issued at END of phase j; w_compute consumes it at START of phase j+1's
// W-section -- gap ~350-450cy < global-load latency (200-900cy). The
// compiler's s_waitcnt vmcnt(0) before the first pfa use stalls the W-waves
// every phase. Balance/barrier changes never touched this.
// R17 = R12 + PREFETCH DEPTH 2, nothing else:
//   - two pf register sets, ping-ponged by phase parity; phase j consumes
//     set[j&1] (loaded 2 phases ~= 1400cy earlier, covers HBM latency) and
//     refills set[j&1] with slice z+4.
//   - main loop restructured 4x9 -> 2x18-unrolled so set parity (ph&1), SW/SH
//     parity, and the q-ring index (ph%9) all stay compile-time static
//     (18 == 0 mod 2 and mod 9).
//   - roles/buffers/guards IDENTICAL to R12: H = tid<160, W = tid>=128,
//     F = all; SW dbuf, SH dbuf, one LDS-only barrier per slice.
// Watch: VGPR ~90 (cap 128), WRITE_SIZE must stay 31.5KB (MB => spill).

#define DD 160
#define HH 192
#define WW 224
#define W4 56                 // WW/4
#define SLICE (HH * WW)
#define S4 (SLICE / 4)
#define NVOX (DD * SLICE)
#define TW 32
#define TH 8
#define DCH 28                // grid.z = 6 -> 1008 blocks
#define ITERS (DCH + 8)       // 36 = 2 * 18 (phase-static ring + parity)
#define NTHR 256
#define SW_RS 36              // b128-aligned rows; 0-conflict measured (R5/R7)
#define SW_CS (16 * SW_RS)    // 576 floats: 16 rows = TH + 8
#define SH_SZ (TH * TW * 5)   // 1280 floats
#define EPS 1e-5f
#define INV_WSUM (1.0f / 729.0f)

// Barrier that orders LDS only: s_waitcnt imm 0xC07F = lgkmcnt(0), vmcnt(63),
// expcnt(7) -> in-flight GLOBAL loads stay in flight across the barrier.
__device__ __forceinline__ void bar_lds_only() {
    __asm__ volatile("" ::: "memory");
    __builtin_amdgcn_s_waitcnt(0xC07F);
    __builtin_amdgcn_s_barrier();
    __asm__ volatile("" ::: "memory");
}

__global__ __launch_bounds__(NTHR, 4) void ncc_fused(const float* __restrict__ I,
                                                     const float* __restrict__ J,
                                                     float* __restrict__ out) {
    __shared__ float SW0[5 * SW_CS], SW1[5 * SW_CS];   // 11.52 KB each
    __shared__ float SH0[SH_SZ], SH1[SH_SZ];           // 5.12 KB each
    __shared__ float wred[NTHR / 64];

    const int tid = threadIdx.x;
    const int tx = tid & 31, ty = tid >> 5;    // F mapping: 32 x 8
    const int wlo = blockIdx.x * TW;
    const int hlo = blockIdx.y * TH;
    const int dlo = blockIdx.z * DCH;

    // W-group (tid >= 128): 16 rows x 8 f4-col groups
    const int wid = tid - 128;
    const int wr = wid >> 3, wc = wid & 7;
    const int gh = hlo - 4 + wr;
    const bool hok = (gh >= 0) && (gh < HH);
    const int gf0 = (wlo >> 2) - 1 + wc;

    // H-group (tid < 160): 5 channels x 32 cols, 8 out-rows each (16 reads)
    const int hcol = tid & 31, hch = tid >> 5;

    const float4* Iv = (const float4*)I;
    const float4* Jv = (const float4*)J;

    // prefetch registers: TWO sets (depth-2 pipeline), 12 floats per array
    float pfa0[12], pfb0[12], pfa1[12], pfb1[12];

#define DEF_WLOAD(NAME, PA, PB)                                               \
    auto NAME = [&](int z) {                                                  \
        const bool zok = (z >= 0) && (z < DD) && hok;                         \
        const int rowb = z * S4 + gh * W4;                                    \
        _Pragma("unroll")                                                     \
        for (int k = 0; k < 3; ++k) {                                         \
            const int f = gf0 + k;                                            \
            float4 a = make_float4(0.f, 0.f, 0.f, 0.f);                       \
            float4 b = make_float4(0.f, 0.f, 0.f, 0.f);                       \
            if (zok && f >= 0 && f < W4) { a = Iv[rowb + f]; b = Jv[rowb + f]; } \
            PA[4*k] = a.x; PA[4*k+1] = a.y; PA[4*k+2] = a.z; PA[4*k+3] = a.w; \
            PB[4*k] = b.x; PB[4*k+1] = b.y; PB[4*k+2] = b.z; PB[4*k+3] = b.w; \
        }                                                                     \
    }
    DEF_WLOAD(w_load0, pfa0, pfb0);
    DEF_WLOAD(w_load1, pfa1, pfb1);

#define DEF_WCOMP(NAME, PA, PB)                                               \
    auto NAME = [&](float* dst) {                                             \
        float* wp = dst + wr * SW_RS + 4 * wc;                                \
        _Pragma("unroll")                                                     \
        for (int ch = 0; ch < 5; ++ch) {                                      \
            float v[12];                                                      \
            _Pragma("unroll")                                                 \
            for (int k = 0; k < 12; ++k)                                      \
                v[k] = (ch == 0) ? PA[k]                                      \
                     : (ch == 1) ? PB[k]                                      \
                     : (ch == 2) ? PA[k] * PA[k]                              \
                     : (ch == 3) ? PB[k] * PB[k]                              \
                     :             PA[k] * PB[k];                             \
            float s = v[0];                                                   \
            _Pragma("unroll")                                                 \
            for (int k = 1; k < 9; ++k) s += v[k];                            \
            float4 o;                                                         \
            o.x = s;                                                          \
            s += v[9]  - v[0]; o.y = s;                                       \
            s += v[10] - v[1]; o.z = s;                                       \
            s += v[11] - v[2]; o.w = s;                                       \
            *(float4*)(wp + ch * SW_CS) = o;                                  \
        }                                                                     \
    }
    DEF_WCOMP(w_comp0, pfa0, pfb0);
    DEF_WCOMP(w_comp1, pfa1, pfb1);

    auto h_phase = [&](const float* swSrc, float* shDst) {  // 9-tap H slide
        const float* p = swSrc + hch * SW_CS + hcol;
        float v[16];
        #pragma unroll
        for (int r = 0; r < 16; r += 2) {       // pairs -> ds_read2_b32
            const float* pr = p + r * SW_RS;
            v[r]     = pr[0];
            v[r + 1] = pr[SW_RS];
        }
        float s = v[0];
        #pragma unroll
        for (int r = 1; r < 9; ++r) s += v[r];
        float* o = shDst + hcol * 5 + hch;      // [row][col][ch]
        float prev = s;
        o[0] = s;
        #pragma unroll
        for (int r = 1; r < TH; ++r) {
            prev += v[r + 8] - v[r - 1];
            o[r * (TW * 5)] = prev;
        }
    };

    float q0[9], q1[9], q2[9], q3[9], q4[9];
    #pragma unroll
    for (int k = 0; k < 9; ++k) { q0[k]=0.f; q1[k]=0.f; q2[k]=0.f; q3[k]=0.f; q4[k]=0.f; }
    float r0=0.f, r1=0.f, r2=0.f, r3=0.f, r4=0.f;
    float acc = 0.f;

    // ---- prologue: W(0)->SW0 via set0, then W(1) and steady-state fill ----
    const int z0 = dlo - 4;
    if (tid >= 128) {
        w_load0(z0);
        if (z0 >= 0) w_comp0(SW0);      // z0 < DD always (dlo <= 140)
        w_load0(z0 + 1);
    }
    bar_lds_only();

    // P0: H(0); W(1) consumes set0; fill set0 <- slice z0+2 (for j=0),
    //     set1 <- slice z0+3 (for j=1).
    if (tid < 160 && z0 >= 0) h_phase(SW0, SH0);
    if (tid >= 128) {
        const int z1 = z0 + 1;
        if (z1 >= 0 && z1 < DD) w_comp0(SW1);
        w_load0(z0 + 2);
        w_load1(z0 + 3);
    }

    // ---- main: 36 phases = 2 x 18 (ph%9 ring, ph&1 parity both static) ----
    #pragma unroll 1
    for (int g = 0; g < 2; ++g) {
        #pragma unroll
        for (int ph = 0; ph < 18; ++ph) {
            const int j = 18 * g + ph;
            const int z = dlo - 4 + j;               // slice consumed by F(j)
            bar_lds_only();   // orders: H(j)->F(j), W(j+1)->H(j+1), bufs freed

            // F(j): issue LDS reads first
            const bool val = (z >= 0) && (z < DD);   // block-uniform
            float* shR = (ph & 1) ? SH1 : SH0;
            float w0=0.f, w1=0.f, w2=0.f, w3=0.f, w4=0.f;
            if (val) {
                const float* pF = shR + (ty * TW + tx) * 5;
                w0 = pF[0]; w1 = pF[1]; w2 = pF[2]; w3 = pF[3]; w4 = pF[4];
            }

            // H(j+1): SW[(j+1)&1] -> SH[(j+1)&1]   (guard j+1 <= ITERS-1)
            if ((g == 0 || ph < 17) && tid < 160) {
                const int zh = z + 1;
                if (zh >= 0 && zh < DD)
                    h_phase((ph & 1) ? SW0 : SW1, (ph & 1) ? SH0 : SH1);
            }

            // W(j+2): consume set[j&1] (slice z+2, loaded 2 phases ago);
            // refill set[j&1] with slice z+4.   (guard j+2 <= ITERS-1)
            if ((g == 0 || ph < 16) && tid >= 128) {
                const int zw = z + 2;
                if ((ph & 1) == 0) {
                    if (zw >= 0 && zw < DD) w_comp0((ph & 1) ? SW1 : SW0);
                    w_load0(z + 4);
                } else {
                    if (zw >= 0 && zw < DD) w_comp1((ph & 1) ? SW1 : SW0);
                    w_load1(z + 4);
                }
            }

            // ring update + cc
            const int rq = ph % 9;                   // static after unroll
            r0 += w0 - q0[rq]; q0[rq] = w0;
            r1 += w1 - q1[rq]; q1[rq] = w1;
            r2 += w2 - q2[rq]; q2[rq] = w2;
            r3 += w3 - q3[rq]; q3[rq] = w3;
            r4 += w4 - q4[rq]; q4[rq] = w4;

            if ((g > 0 || ph >= 8) && (dlo + j - 8) < DD) {  // overhang to 167
                float cross = r4 - r0 * r1 * INV_WSUM;
                float iv    = r2 - r0 * r0 * INV_WSUM;
                float jv    = r3 - r1 * r1 * INV_WSUM;
                acc += cross * cross * __builtin_amdgcn_rcpf(iv * jv + EPS);
            }
        }
    }

    // ---- block reduction -> one atomic (cold path: full __syncthreads ok) ----
    #pragma unroll
    for (int off = 32; off > 0; off >>= 1) acc += __shfl_down(acc, off, 64);
    if ((tid & 63) == 0) wred[tid >> 6] = acc;
    __syncthreads();
    if (tid == 0) {
        float t = 0.f;
        #pragma unroll
        for (int k = 0; k < NTHR / 64; ++k) t += wred[k];
        atomicAdd(out, t * (-1.0f / (float)NVOX));
    }
}

extern "C" void kernel_launch(void* const* d_in, const int* in_sizes, int n_in,
                              void* d_out, int out_size, void* d_ws, size_t ws_size,
                              hipStream_t stream) {
    const float* I = (const float*)d_in[0];
    const float* J = (const float*)d_in[1];
    float* out = (float*)d_out;

    hipMemsetAsync(d_out, 0, sizeof(float), stream);  // harness re-poisons d_out

    dim3 blk(NTHR, 1, 1);
    dim3 grd(WW / TW, HH / TH, (DD + DCH - 1) / DCH); // 7 x 24 x 6 = 1008 blocks
    ncc_fused<<<grd, blk, 0, stream>>>(I, J, out);
}

// Round 11
// 145.470 us; speedup vs baseline: 1.6102x; 1.6102x over previous
//
#include <hip/hip_runtime.h>

// NCC loss, win=9, (1,1,160,192,224) fp32 -> scalar. Fully fused, round 18.
// R17 post-mortem: depth-2 prefetch SPILLED (WRITE_SIZE 83MB, dur 161us).
// Cause, with arithmetic: __launch_bounds__(256,4) -> 4 waves/SIMD -> unified
// VGPR+AGPR budget 128/wave. R12 ~109 (64 arch + ~45 AGPR ring) fits; R17's
// +24 pf regs -> 133 > 128 -> scratch. The pipeline itself passed (absmax 0).
// Latency model (R12): 3800 cy wall/block-phase vs ~390 VALU + ~280 LDS-pipe
// -> critical path is the pf-load->w_compute vmcnt wait (~2500-3000 cy under
// load, cross-XCD halo re-fetches). Depth-2 stretches load->use to ~2 phases.
// R18 = R17 with __launch_bounds__(256, 3): budget 170 regs/wave (133 fits).
// Cost: block cap 4->3/CU -- measured occupancy was ~2.8 blocks effective, so
// nothing real is lost. Everything else identical to R17:
//   - two pf register sets ping-ponged by phase parity; phase j consumes
//     set[j&1] (loaded 2 phases earlier), refills it with slice z+4.
//   - main loop 2 x 18-unrolled (ph&1, ph%9, SW/SH parity all static).
//   - roles/buffers/guards = R12: H = tid<160, W = tid>=128, F = all;
//     SW dbuf, SH dbuf, one LDS-only barrier per slice (vmcnt spans it).
// Watch: WRITE_SIZE must return to ~31.5KB (MB-scale => still spilling).

#define DD 160
#define HH 192
#define WW 224
#define W4 56                 // WW/4
#define SLICE (HH * WW)
#define S4 (SLICE / 4)
#define NVOX (DD * SLICE)
#define TW 32
#define TH 8
#define DCH 28                // grid.z = 6 -> 1008 blocks
#define ITERS (DCH + 8)       // 36 = 2 * 18 (phase-static ring + parity)
#define NTHR 256
#define SW_RS 36              // b128-aligned rows; 0-conflict measured (R5/R7)
#define SW_CS (16 * SW_RS)    // 576 floats: 16 rows = TH + 8
#define SH_SZ (TH * TW * 5)   // 1280 floats
#define EPS 1e-5f
#define INV_WSUM (1.0f / 729.0f)

// Barrier that orders LDS only: s_waitcnt imm 0xC07F = lgkmcnt(0), vmcnt(63),
// expcnt(7) -> in-flight GLOBAL loads stay in flight across the barrier.
__device__ __forceinline__ void bar_lds_only() {
    __asm__ volatile("" ::: "memory");
    __builtin_amdgcn_s_waitcnt(0xC07F);
    __builtin_amdgcn_s_barrier();
    __asm__ volatile("" ::: "memory");
}

__global__ __launch_bounds__(NTHR, 3) void ncc_fused(const float* __restrict__ I,
                                                     const float* __restrict__ J,
                                                     float* __restrict__ out) {
    __shared__ float SW0[5 * SW_CS], SW1[5 * SW_CS];   // 11.52 KB each
    __shared__ float SH0[SH_SZ], SH1[SH_SZ];           // 5.12 KB each
    __shared__ float wred[NTHR / 64];

    const int tid = threadIdx.x;
    const int tx = tid & 31, ty = tid >> 5;    // F mapping: 32 x 8
    const int wlo = blockIdx.x * TW;
    const int hlo = blockIdx.y * TH;
    const int dlo = blockIdx.z * DCH;

    // W-group (tid >= 128): 16 rows x 8 f4-col groups
    const int wid = tid - 128;
    const int wr = wid >> 3, wc = wid & 7;
    const int gh = hlo - 4 + wr;
    const bool hok = (gh >= 0) && (gh < HH);
    const int gf0 = (wlo >> 2) - 1 + wc;

    // H-group (tid < 160): 5 channels x 32 cols, 8 out-rows each (16 reads)
    const int hcol = tid & 31, hch = tid >> 5;

    const float4* Iv = (const float4*)I;
    const float4* Jv = (const float4*)J;

    // prefetch registers: TWO sets (depth-2 pipeline), 12 floats per array
    float pfa0[12], pfb0[12], pfa1[12], pfb1[12];

#define DEF_WLOAD(NAME, PA, PB)                                               \
    auto NAME = [&](int z) {                                                  \
        const bool zok = (z >= 0) && (z < DD) && hok;                         \
        const int rowb = z * S4 + gh * W4;                                    \
        _Pragma("unroll")                                                     \
        for (int k = 0; k < 3; ++k) {                                         \
            const int f = gf0 + k;                                            \
            float4 a = make_float4(0.f, 0.f, 0.f, 0.f);                       \
            float4 b = make_float4(0.f, 0.f, 0.f, 0.f);                       \
            if (zok && f >= 0 && f < W4) { a = Iv[rowb + f]; b = Jv[rowb + f]; } \
            PA[4*k] = a.x; PA[4*k+1] = a.y; PA[4*k+2] = a.z; PA[4*k+3] = a.w; \
            PB[4*k] = b.x; PB[4*k+1] = b.y; PB[4*k+2] = b.z; PB[4*k+3] = b.w; \
        }                                                                     \
    }
    DEF_WLOAD(w_load0, pfa0, pfb0);
    DEF_WLOAD(w_load1, pfa1, pfb1);

#define DEF_WCOMP(NAME, PA, PB)                                               \
    auto NAME = [&](float* dst) {                                             \
        float* wp = dst + wr * SW_RS + 4 * wc;                                \
        _Pragma("unroll")                                                     \
        for (int ch = 0; ch < 5; ++ch) {                                      \
            float v[12];                                                      \
            _Pragma("unroll")                                                 \
            for (int k = 0; k < 12; ++k)                                      \
                v[k] = (ch == 0) ? PA[k]                                      \
                     : (ch == 1) ? PB[k]                                      \
                     : (ch == 2) ? PA[k] * PA[k]                              \
                     : (ch == 3) ? PB[k] * PB[k]                              \
                     :             PA[k] * PB[k];                             \
            float s = v[0];                                                   \
            _Pragma("unroll")                                                 \
            for (int k = 1; k < 9; ++k) s += v[k];                            \
            float4 o;                                                         \
            o.x = s;                                                          \
            s += v[9]  - v[0]; o.y = s;                                       \
            s += v[10] - v[1]; o.z = s;                                       \
            s += v[11] - v[2]; o.w = s;                                       \
            *(float4*)(wp + ch * SW_CS) = o;                                  \
        }                                                                     \
    }
    DEF_WCOMP(w_comp0, pfa0, pfb0);
    DEF_WCOMP(w_comp1, pfa1, pfb1);

    auto h_phase = [&](const float* swSrc, float* shDst) {  // 9-tap H slide
        const float* p = swSrc + hch * SW_CS + hcol;
        float v[16];
        #pragma unroll
        for (int r = 0; r < 16; r += 2) {       // pairs -> ds_read2_b32
            const float* pr = p + r * SW_RS;
            v[r]     = pr[0];
            v[r + 1] = pr[SW_RS];
        }
        float s = v[0];
        #pragma unroll
        for (int r = 1; r < 9; ++r) s += v[r];
        float* o = shDst + hcol * 5 + hch;      // [row][col][ch]
        float prev = s;
        o[0] = s;
        #pragma unroll
        for (int r = 1; r < TH; ++r) {
            prev += v[r + 8] - v[r - 1];
            o[r * (TW * 5)] = prev;
        }
    };

    float q0[9], q1[9], q2[9], q3[9], q4[9];
    #pragma unroll
    for (int k = 0; k < 9; ++k) { q0[k]=0.f; q1[k]=0.f; q2[k]=0.f; q3[k]=0.f; q4[k]=0.f; }
    float r0=0.f, r1=0.f, r2=0.f, r3=0.f, r4=0.f;
    float acc = 0.f;

    // ---- prologue: W(0)->SW0 via set0, then W(1) and steady-state fill ----
    const int z0 = dlo - 4;
    if (tid >= 128) {
        w_load0(z0);
        if (z0 >= 0) w_comp0(SW0);      // z0 < DD always (dlo <= 140)
        w_load0(z0 + 1);
    }
    bar_lds_only();

    // P0: H(0); W(1) consumes set0; fill set0 <- slice z0+2 (for j=0),
    //     set1 <- slice z0+3 (for j=1).
    if (tid < 160 && z0 >= 0) h_phase(SW0, SH0);
    if (tid >= 128) {
        const int z1 = z0 + 1;
        if (z1 >= 0 && z1 < DD) w_comp0(SW1);
        w_load0(z0 + 2);
        w_load1(z0 + 3);
    }

    // ---- main: 36 phases = 2 x 18 (ph%9 ring, ph&1 parity both static) ----
    #pragma unroll 1
    for (int g = 0; g < 2; ++g) {
        #pragma unroll
        for (int ph = 0; ph < 18; ++ph) {
            const int j = 18 * g + ph;
            const int z = dlo - 4 + j;               // slice consumed by F(j)
            bar_lds_only();   // orders: H(j)->F(j), W(j+1)->H(j+1), bufs freed

            // F(j): issue LDS reads first
            const bool val = (z >= 0) && (z < DD);   // block-uniform
            float* shR = (ph & 1) ? SH1 : SH0;
            float w0=0.f, w1=0.f, w2=0.f, w3=0.f, w4=0.f;
            if (val) {
                const float* pF = shR + (ty * TW + tx) * 5;
                w0 = pF[0]; w1 = pF[1]; w2 = pF[2]; w3 = pF[3]; w4 = pF[4];
            }

            // H(j+1): SW[(j+1)&1] -> SH[(j+1)&1]   (guard j+1 <= ITERS-1)
            if ((g == 0 || ph < 17) && tid < 160) {
                const int zh = z + 1;
                if (zh >= 0 && zh < DD)
                    h_phase((ph & 1) ? SW0 : SW1, (ph & 1) ? SH0 : SH1);
            }

            // W(j+2): consume set[j&1] (slice z+2, loaded 2 phases ago);
            // refill set[j&1] with slice z+4.   (guard j+2 <= ITERS-1)
            if ((g == 0 || ph < 16) && tid >= 128) {
                const int zw = z + 2;
                if ((ph & 1) == 0) {
                    if (zw >= 0 && zw < DD) w_comp0((ph & 1) ? SW1 : SW0);
                    w_load0(z + 4);
                } else {
                    if (zw >= 0 && zw < DD) w_comp1((ph & 1) ? SW1 : SW0);
                    w_load1(z + 4);
                }
            }

            // ring update + cc
            const int rq = ph % 9;                   // static after unroll
            r0 += w0 - q0[rq]; q0[rq] = w0;
            r1 += w1 - q1[rq]; q1[rq] = w1;
            r2 += w2 - q2[rq]; q2[rq] = w2;
            r3 += w3 - q3[rq]; q3[rq] = w3;
            r4 += w4 - q4[rq]; q4[rq] = w4;

            if ((g > 0 || ph >= 8) && (dlo + j - 8) < DD) {  // overhang to 167
                float cross = r4 - r0 * r1 * INV_WSUM;
                float iv    = r2 - r0 * r0 * INV_WSUM;
                float jv    = r3 - r1 * r1 * INV_WSUM;
                acc += cross * cross * __builtin_amdgcn_rcpf(iv * jv + EPS);
            }
        }
    }

    // ---- block reduction -> one atomic (cold path: full __syncthreads ok) ----
    #pragma unroll
    for (int off = 32; off > 0; off >>= 1) acc += __shfl_down(acc, off, 64);
    if ((tid & 63) == 0) wred[tid >> 6] = acc;
    __syncthreads();
    if (tid == 0) {
        float t = 0.f;
        #pragma unroll
        for (int k = 0; k < NTHR / 64; ++k) t += wred[k];
        atomicAdd(out, t * (-1.0f / (float)NVOX));
    }
}

extern "C" void kernel_launch(void* const* d_in, const int* in_sizes, int n_in,
                              void* d_out, int out_size, void* d_ws, size_t ws_size,
                              hipStream_t stream) {
    const float* I = (const float*)d_in[0];
    const float* J = (const float*)d_in[1];
    float* out = (float*)d_out;

    hipMemsetAsync(d_out, 0, sizeof(float), stream);  // harness re-poisons d_out

    dim3 blk(NTHR, 1, 1);
    dim3 grd(WW / TW, HH / TH, (DD + DCH - 1) / DCH); // 7 x 24 x 6 = 1008 blocks
    ncc_fused<<<grd, blk, 0, stream>>>(I, J, out);
}

// Round 12
// 124.414 us; speedup vs baseline: 1.8827x; 1.1692x over previous
//
#include <hip/hip_runtime.h>

// NCC loss, win=9, (1,1,160,192,224) fp32 -> scalar. Fully fused, round 19.
// R17/R18 post-mortem: depth-2 prefetch loses at ANY register price (spill at
// 4 blocks/CU, occupancy collapse at 3). Latency theory demoted: ~4 blocks/CU
// already cover the vmcnt window. Surviving model (7 data pts): dur ~=
// critical-wave issue / achievable busy. R12's critical wave = wave 2 doing
// H+W+F ~300 inst/phase (H=tid<160 overlaps W=tid>=128). R15 proved balance
// raises busy to 60% but duplicated the load path (+64% work).
// R19 = R12 with ONE change: roles made wave-disjoint WITHOUT duplication:
//   - H -> tid<128 (waves 0,1): pass1 = ch0-3 (tid>>5, tid&31) -- identical
//     read pattern to R12's wave-0/1 share (0-conflict); pass2 = ch4 on
//     tid 96-127 (wave 1 issues one extra masked h_phase).
//   - W stays tid>=128 (waves 2,3), loads only there (no duplication).
//   - F on all threads. Critical wave 300 -> ~213 (-29%), total work flat.
// Buffers/parity/barriers/DCH/launch_bounds identical to R12 (58.6us best):
//   SW dbuf, SH dbuf, ONE LDS-only barrier per slice (vmcnt spans it);
//   bar; { F(j): SH[j&1] || H(j+1): SW[(j+1)&1]->SH[(j+1)&1]
//        || W(j+2): pf -> SW[j&1]; w_load(z+3) }   DCH=28, 1008 blocks.

#define DD 160
#define HH 192
#define WW 224
#define W4 56                 // WW/4
#define SLICE (HH * WW)
#define S4 (SLICE / 4)
#define NVOX (DD * SLICE)
#define TW 32
#define TH 8
#define DCH 28                // grid.z = 6 -> 1008 blocks
#define ITERS (DCH + 8)       // 36 = 4 * 9 (phase-static ring)
#define NTHR 256
#define SW_RS 36              // b128-aligned rows; 0-conflict measured (R5/R7)
#define SW_CS (16 * SW_RS)    // 576 floats: 16 rows = TH + 8
#define SH_SZ (TH * TW * 5)   // 1280 floats
#define EPS 1e-5f
#define INV_WSUM (1.0f / 729.0f)

// Barrier that orders LDS only: s_waitcnt imm 0xC07F = lgkmcnt(0), vmcnt(63),
// expcnt(7) -> in-flight GLOBAL loads stay in flight across the barrier.
__device__ __forceinline__ void bar_lds_only() {
    __asm__ volatile("" ::: "memory");
    __builtin_amdgcn_s_waitcnt(0xC07F);
    __builtin_amdgcn_s_barrier();
    __asm__ volatile("" ::: "memory");
}

__global__ __launch_bounds__(NTHR, 4) void ncc_fused(const float* __restrict__ I,
                                                     const float* __restrict__ J,
                                                     float* __restrict__ out) {
    __shared__ float SW0[5 * SW_CS], SW1[5 * SW_CS];   // 11.52 KB each
    __shared__ float SH0[SH_SZ], SH1[SH_SZ];           // 5.12 KB each
    __shared__ float wred[NTHR / 64];

    const int tid = threadIdx.x;
    const int tx = tid & 31, ty = tid >> 5;    // F mapping: 32 x 8
    const int wlo = blockIdx.x * TW;
    const int hlo = blockIdx.y * TH;
    const int dlo = blockIdx.z * DCH;

    // W-group (tid >= 128): 16 rows x 8 f4-col groups
    const int wid = tid - 128;
    const int wr = wid >> 3, wc = wid & 7;
    const int gh = hlo - 4 + wr;
    const bool hok = (gh >= 0) && (gh < HH);
    const int gf0 = (wlo >> 2) - 1 + wc;

    // H-group (tid < 128): pass1 ch0-3; pass2 ch4 on tid 96-127 (wave 1)
    const int hcol = tid & 31, hch = tid >> 5;
    const bool h2 = (tid >= 96) && (tid < 128);
    const int h2col = tid - 96;

    const float4* Iv = (const float4*)I;
    const float4* Jv = (const float4*)J;

    // prefetch registers: one slice-row of raw I/J (12 floats each)
    float pfa[12], pfb[12];

    auto w_load = [&](int z) {   // fill pfa/pfb for slice z (zeros if OOB)
        const bool zok = (z >= 0) && (z < DD) && hok;
        const int rowb = z * S4 + gh * W4;
        #pragma unroll
        for (int k = 0; k < 3; ++k) {
            const int f = gf0 + k;
            float4 a = make_float4(0.f, 0.f, 0.f, 0.f);
            float4 b = make_float4(0.f, 0.f, 0.f, 0.f);
            if (zok && f >= 0 && f < W4) { a = Iv[rowb + f]; b = Jv[rowb + f]; }
            pfa[4*k] = a.x; pfa[4*k+1] = a.y; pfa[4*k+2] = a.z; pfa[4*k+3] = a.w;
            pfb[4*k] = b.x; pfb[4*k+1] = b.y; pfb[4*k+2] = b.z; pfb[4*k+3] = b.w;
        }
    };

    auto w_compute = [&](float* dst) {   // slide 9-tap W-sums from pfa/pfb -> dst
        float* wp = dst + wr * SW_RS + 4 * wc;
        #pragma unroll
        for (int ch = 0; ch < 5; ++ch) {
            float v[12];
            #pragma unroll
            for (int k = 0; k < 12; ++k)
                v[k] = (ch == 0) ? pfa[k]
                     : (ch == 1) ? pfb[k]
                     : (ch == 2) ? pfa[k] * pfa[k]
                     : (ch == 3) ? pfb[k] * pfb[k]
                     :             pfa[k] * pfb[k];
            float s = v[0];
            #pragma unroll
            for (int k = 1; k < 9; ++k) s += v[k];
            float4 o;
            o.x = s;
            s += v[9]  - v[0]; o.y = s;
            s += v[10] - v[1]; o.z = s;
            s += v[11] - v[2]; o.w = s;
            *(float4*)(wp + ch * SW_CS) = o;   // b128, 16B-aligned
        }
    };

    auto h_phase = [&](const float* swSrc, float* shDst, int col, int ch) {
        const float* p = swSrc + ch * SW_CS + col;
        float v[16];
        #pragma unroll
        for (int r = 0; r < 16; r += 2) {       // pairs -> ds_read2_b32
            const float* pr = p + r * SW_RS;
            v[r]     = pr[0];
            v[r + 1] = pr[SW_RS];
        }
        float s = v[0];
        #pragma unroll
        for (int r = 1; r < 9; ++r) s += v[r];
        float* o = shDst + col * 5 + ch;        // [row][col][ch]
        float prev = s;
        o[0] = s;
        #pragma unroll
        for (int r = 1; r < TH; ++r) {
            prev += v[r + 8] - v[r - 1];
            o[r * (TW * 5)] = prev;
        }
    };

    float q0[9], q1[9], q2[9], q3[9], q4[9];
    #pragma unroll
    for (int k = 0; k < 9; ++k) { q0[k]=0.f; q1[k]=0.f; q2[k]=0.f; q3[k]=0.f; q4[k]=0.f; }
    float r0=0.f, r1=0.f, r2=0.f, r3=0.f, r4=0.f;
    float acc = 0.f;

    // ---- prologue: W(0) -> SW0, prefetch slice 1 ----
    const int z0 = dlo - 4;
    if (tid >= 128) {
        w_load(z0);
        if (z0 >= 0) w_compute(SW0);        // z0 < DD always (dlo <= 140)
        w_load(z0 + 1);
    }
    bar_lds_only();

    // ---- P0: H(0), W(1), prefetch slice 2 (no F yet) ----
    if (tid < 128 && z0 >= 0) {
        h_phase(SW0, SH0, hcol, hch);
        if (h2) h_phase(SW0, SH0, h2col, 4);
    }
    if (tid >= 128) {
        const int z1 = z0 + 1;
        if (z1 >= 0 && z1 < DD) w_compute(SW1);
        w_load(z0 + 2);
    }

    // ---- main: 36 phases, ONE barrier each ----
    #pragma unroll 1
    for (int g = 0; g < 4; ++g) {
        #pragma unroll
        for (int ph = 0; ph < 9; ++ph) {
            const int j = 9 * g + ph;
            const int z = dlo - 4 + j;               // slice consumed by F(j)
            bar_lds_only();   // orders: H(j)->F(j), W(j+1)->H(j+1), bufs freed

            // F(j): issue LDS reads first
            const bool val = (z >= 0) && (z < DD);   // block-uniform
            float* shR = (j & 1) ? SH1 : SH0;
            float w0=0.f, w1=0.f, w2=0.f, w3=0.f, w4=0.f;
            if (val) {
                const float* pF = shR + (ty * TW + tx) * 5;
                w0 = pF[0]; w1 = pF[1]; w2 = pF[2]; w3 = pF[3]; w4 = pF[4];
            }

            // H(j+1): SW[(j+1)&1] -> SH[(j+1)&1]   (guard j+1 <= ITERS-1)
            if ((g < 3 || ph < 8) && tid < 128) {
                const int zh = z + 1;
                if (zh >= 0 && zh < DD) {
                    const float* src = (j & 1) ? SW0 : SW1;
                    float* dst = (j & 1) ? SH0 : SH1;
                    h_phase(src, dst, hcol, hch);
                    if (h2) h_phase(src, dst, h2col, 4);
                }
            }

            // W(j+2): pf regs -> SW[(j+2)&1]; refill pf   (guard j+2 <= ITERS-1)
            if ((g < 3 || ph < 7) && tid >= 128) {
                const int zw = z + 2;
                if (zw >= 0 && zw < DD) w_compute((j & 1) ? SW1 : SW0);
                w_load(z + 3);
            }

            // ring update + cc
            r0 += w0 - q0[ph]; q0[ph] = w0;
            r1 += w1 - q1[ph]; q1[ph] = w1;
            r2 += w2 - q2[ph]; q2[ph] = w2;
            r3 += w3 - q3[ph]; q3[ph] = w3;
            r4 += w4 - q4[ph]; q4[ph] = w4;

            if (j >= 8 && (dlo + j - 8) < DD) {   // last chunk overhangs to 167
                float cross = r4 - r0 * r1 * INV_WSUM;
                float iv    = r2 - r0 * r0 * INV_WSUM;
                float jv    = r3 - r1 * r1 * INV_WSUM;
                acc += cross * cross * __builtin_amdgcn_rcpf(iv * jv + EPS);
            }
        }
    }

    // ---- block reduction -> one atomic (cold path: full __syncthreads ok) ----
    #pragma unroll
    for (int off = 32; off > 0; off >>= 1) acc += __shfl_down(acc, off, 64);
    if ((tid & 63) == 0) wred[tid >> 6] = acc;
    __syncthreads();
    if (tid == 0) {
        float t = 0.f;
        #pragma unroll
        for (int k = 0; k < NTHR / 64; ++k) t += wred[k];
        atomicAdd(out, t * (-1.0f / (float)NVOX));
    }
}

extern "C" void kernel_launch(void* const* d_in, const int* in_sizes, int n_in,
                              void* d_out, int out_size, void* d_ws, size_t ws_size,
                              hipStream_t stream) {
    const float* I = (const float*)d_in[0];
    const float* J = (const float*)d_in[1];
    float* out = (float*)d_out;

    hipMemsetAsync(d_out, 0, sizeof(float), stream);  // harness re-poisons d_out

    dim3 blk(NTHR, 1, 1);
    dim3 grd(WW / TW, HH / TH, (DD + DCH - 1) / DCH); // 7 x 24 x 6 = 1008 blocks
    ncc_fused<<<grd, blk, 0, stream>>>(I, J, out);
}